// Round 2
// baseline (536.113 us; speedup 1.0000x reference)
//
#include <hip/hip_runtime.h>

#define LRELU_SLOPE 0.2f

// ---------------------------------------------------------------------------
// Workspace layout (floats):
//   buf1   [N*16] : per (node,head) interleaved {denom, numer} pairs (layer 1)
//   buf2   [N*4]  : per node {denom2, numer2_0, numer2_1, pad}     (layer 2)
//   nodef  [N*4]  : per node {h2_0, h2_1, alpha_src2, alpha_dst2}
//   consts [16]   : cs1[8], cd1[8]
// ---------------------------------------------------------------------------

// K1: zero the atomic accumulators + d_out, compute per-head constants
//   cs1[h] = dot(W1[h*64:(h+1)*64], a_src1[h,:]); cd1 likewise with a_dst1.
__global__ void k_init(float* __restrict__ zero_region, long nzero,
                       const float* __restrict__ W1,
                       const float* __restrict__ as1,
                       const float* __restrict__ ad1,
                       float* __restrict__ consts,
                       float* __restrict__ out) {
    long i = (long)blockIdx.x * blockDim.x + threadIdx.x;
    long stride = (long)gridDim.x * blockDim.x;
    for (long j = i; j < nzero; j += stride) zero_region[j] = 0.f;
    if (blockIdx.x == 0) {
        if (threadIdx.x < 16) {
            int h = threadIdx.x & 7;
            const float* a = (threadIdx.x < 8) ? as1 : ad1;
            float acc = 0.f;
            #pragma unroll
            for (int f = 0; f < 64; ++f) acc += W1[h * 64 + f] * a[h * 64 + f];
            consts[threadIdx.x] = acc;
        }
        if (threadIdx.x == 0) { out[0] = 0.f; out[1] = 0.f; }
    }
}

// K2: layer-1 edge pass. e = lrelu(x[s]*cs[h] + x[d]*cd[h]); accumulate
// exp(e) and exp(e)*x[s] per (dst, head). Max-subtraction skipped: the
// softmax ratio is shift-invariant and |e| is small enough for fp32 exp.
// Items [0,E) are graph edges; [E, E+N) are the self-loops.
__global__ void k_edge1(const int* __restrict__ esrc, const int* __restrict__ edst,
                        const float* __restrict__ x, const float* __restrict__ consts,
                        float* __restrict__ buf1, int E, int N) {
    float cs[8], cd[8];
    #pragma unroll
    for (int h = 0; h < 8; ++h) { cs[h] = consts[h]; cd[h] = consts[8 + h]; }
    int total = E + N;
    for (int i = blockIdx.x * blockDim.x + threadIdx.x; i < total;
         i += gridDim.x * blockDim.x) {
        int s, d;
        if (i < E) { s = esrc[i]; d = edst[i]; } else { s = i - E; d = s; }
        float xs = x[s], xd = x[d];
        float* base = buf1 + (size_t)d * 16;
        #pragma unroll
        for (int h = 0; h < 8; ++h) {
            float e = fmaf(xs, cs[h], xd * cd[h]);
            e = e > 0.f ? e : LRELU_SLOPE * e;
            float ex = __expf(e);
            atomicAdd(base + 2 * h, ex);          // denom
            atomicAdd(base + 2 * h + 1, ex * xs); // numer
        }
    }
}

// K3: finish layer 1 per node (s[h] = numer/denom), apply rank-1 feature
// expansion + b1 + ReLU, the 512x2 layer-2 linear, and the two layer-2
// attention dot products. One thread per node; weights staged in LDS
// (all reads are wave-uniform -> broadcast, no bank conflicts).
__global__ __launch_bounds__(256) void k_node(
        const float* __restrict__ buf1,
        const float* __restrict__ W1, const float* __restrict__ b1,
        const float* __restrict__ W2,
        const float* __restrict__ as2, const float* __restrict__ ad2,
        float* __restrict__ nodef, int N) {
    __shared__ float sW1[512], sB1[512], sW2[1024];
    for (int t = threadIdx.x; t < 512; t += 256) { sW1[t] = W1[t]; sB1[t] = b1[t]; }
    for (int t = threadIdx.x; t < 1024; t += 256) sW2[t] = W2[t];
    __syncthreads();
    int n = blockIdx.x * blockDim.x + threadIdx.x;
    if (n >= N) return;
    const float* bn = buf1 + (size_t)n * 16;
    float h20 = 0.f, h21 = 0.f;
    #pragma unroll
    for (int h = 0; h < 8; ++h) {
        float den = bn[2 * h] + 1e-16f;
        float sh = bn[2 * h + 1] / den;
        for (int f = 0; f < 64; ++f) {
            int idx = h * 64 + f;
            float v = fmaf(sW1[idx], sh, sB1[idx]);
            v = fmaxf(v, 0.f);
            h20 = fmaf(v, sW2[2 * idx], h20);
            h21 = fmaf(v, sW2[2 * idx + 1], h21);
        }
    }
    float as_ = h20 * as2[0] + h21 * as2[1];
    float ad_ = h20 * ad2[0] + h21 * ad2[1];
    float4 o; o.x = h20; o.y = h21; o.z = as_; o.w = ad_;
    reinterpret_cast<float4*>(nodef)[n] = o;
}

// K4: layer-2 edge pass (1 head, 2 features). 3 atomics per edge.
__global__ void k_edge2(const int* __restrict__ esrc, const int* __restrict__ edst,
                        const float4* __restrict__ nodef,
                        float* __restrict__ buf2, int E, int N) {
    int total = E + N;
    const float* nf = reinterpret_cast<const float*>(nodef);
    for (int i = blockIdx.x * blockDim.x + threadIdx.x; i < total;
         i += gridDim.x * blockDim.x) {
        int s, d;
        if (i < E) { s = esrc[i]; d = edst[i]; } else { s = i - E; d = s; }
        float4 fs = nodef[s];
        float adw = nf[(size_t)d * 4 + 3];
        float e = fs.z + adw;
        e = e > 0.f ? e : LRELU_SLOPE * e;
        float ex = __expf(e);
        float* b = buf2 + (size_t)d * 4;
        atomicAdd(b, ex);
        atomicAdd(b + 1, ex * fs.x);
        atomicAdd(b + 2, ex * fs.y);
    }
}

// K5: per-node finish layer 2 (+b2), log_softmax over the 2 outputs,
// mean over nodes via block reduction + one atomicAdd pair per block.
__global__ __launch_bounds__(256) void k_final(const float* __restrict__ buf2,
                                               const float* __restrict__ b2,
                                               float* __restrict__ out, int N) {
    int n = blockIdx.x * blockDim.x + threadIdx.x;
    float l0 = 0.f, l1 = 0.f;
    if (n < N) {
        const float* b = buf2 + (size_t)n * 4;
        float inv = 1.f / (b[0] + 1e-16f);
        float o0 = b[1] * inv + b2[0];
        float o1 = b[2] * inv + b2[1];
        float m = fmaxf(o0, o1);
        float z0 = o0 - m, z1 = o1 - m;
        float lse = logf(__expf(z0) + __expf(z1));
        l0 = z0 - lse; l1 = z1 - lse;
    }
    #pragma unroll
    for (int off = 32; off; off >>= 1) {
        l0 += __shfl_down(l0, off);
        l1 += __shfl_down(l1, off);
    }
    __shared__ float w0[4], w1[4];
    int wid = threadIdx.x >> 6, lane = threadIdx.x & 63;
    if (lane == 0) { w0[wid] = l0; w1[wid] = l1; }
    __syncthreads();
    if (threadIdx.x == 0) {
        float s0 = w0[0] + w0[1] + w0[2] + w0[3];
        float s1 = w1[0] + w1[1] + w1[2] + w1[3];
        float invN = 1.f / (float)N;
        atomicAdd(&out[0], s0 * invN);
        atomicAdd(&out[1], s1 * invN);
    }
}

extern "C" void kernel_launch(void* const* d_in, const int* in_sizes, int n_in,
                              void* d_out, int out_size, void* d_ws, size_t ws_size,
                              hipStream_t stream) {
    const float* x   = (const float*)d_in[0];
    const int*   ei  = (const int*)d_in[1];
    const float* W1  = (const float*)d_in[2];
    const float* as1 = (const float*)d_in[3];
    const float* ad1 = (const float*)d_in[4];
    const float* b1  = (const float*)d_in[5];
    const float* W2  = (const float*)d_in[6];
    const float* as2 = (const float*)d_in[7];
    const float* ad2 = (const float*)d_in[8];
    const float* b2  = (const float*)d_in[9];
    int N = in_sizes[0];       // 50000
    int E = in_sizes[1] / 2;   // 400000
    float* out = (float*)d_out;

    float* ws     = (float*)d_ws;
    float* buf1   = ws;                     // N*16
    float* buf2   = ws + (size_t)N * 16;    // N*4
    float* nodef  = ws + (size_t)N * 20;    // N*4
    float* consts = ws + (size_t)N * 24;    // 16

    long nzero = (long)N * 20;              // buf1 + buf2 contiguous
    hipLaunchKernelGGL(k_init, dim3(2048), dim3(256), 0, stream,
                       buf1, nzero, W1, as1, ad1, consts, out);

    int total = E + N;
    int eb = (total + 255) / 256;
    hipLaunchKernelGGL(k_edge1, dim3(eb), dim3(256), 0, stream,
                       ei, ei + E, x, consts, buf1, E, N);

    int nb = (N + 255) / 256;
    hipLaunchKernelGGL(k_node, dim3(nb), dim3(256), 0, stream,
                       buf1, W1, b1, W2, as2, ad2, nodef, N);

    hipLaunchKernelGGL(k_edge2, dim3(eb), dim3(256), 0, stream,
                       ei, ei + E, (const float4*)nodef, buf2, E, N);

    hipLaunchKernelGGL(k_final, dim3(nb), dim3(256), 0, stream,
                       buf2, b2, out, N);
}

// Round 3
// 195.975 us; speedup vs baseline: 2.7356x; 2.7356x over previous
//
#include <hip/hip_runtime.h>

#define LRELU_SLOPE 0.2f

// ---------------------------------------------------------------------------
// Strategy: build a by-destination CSR each call (same work every call), then
// GATHER per node instead of scattering fp32 atomics per edge.
//   round-2 evidence: 7.25M fp32 atomicAdds = 225MB write-through at ~600GB/s
//   (atomics resolve past the per-XCD L2) -> 383us. Gather removes them all.
//
// Workspace layout:
//   nodef  [N*4 floats] : per node {h2_0, h2_1, alpha_src2, alpha_dst2}
//   cnt    [N ints]     : in-degree histogram (excl. self-loop)
//   rowptr [N ints]     : exclusive scan of cnt
//   cursor [N ints]     : scatter cursors (copy of rowptr)
//   colsrc [E ints]     : CSR column (src node id) array
//   consts [16 floats]  : cs1[8], cd1[8]
// ---------------------------------------------------------------------------

// K1: zero cnt + out, compute per-head constants
//   cs1[h] = dot(W1[h*64:(h+1)*64], a_src1[h,:]); cd1 likewise with a_dst1.
__global__ void k_init(int* __restrict__ cnt, int N,
                       const float* __restrict__ W1,
                       const float* __restrict__ as1,
                       const float* __restrict__ ad1,
                       float* __restrict__ consts,
                       float* __restrict__ out) {
    int i = blockIdx.x * blockDim.x + threadIdx.x;
    int stride = gridDim.x * blockDim.x;
    for (int j = i; j < N; j += stride) cnt[j] = 0;
    if (blockIdx.x == 0) {
        if (threadIdx.x < 16) {
            int h = threadIdx.x & 7;
            const float* a = (threadIdx.x < 8) ? as1 : ad1;
            float acc = 0.f;
            #pragma unroll
            for (int f = 0; f < 64; ++f) acc += W1[h * 64 + f] * a[h * 64 + f];
            consts[threadIdx.x] = acc;
        }
        if (threadIdx.x == 0) { out[0] = 0.f; out[1] = 0.f; }
    }
}

// K2: in-degree histogram (int atomics, 1 per edge).
__global__ void k_hist(const int* __restrict__ edst, int* __restrict__ cnt, int E) {
    int i = blockIdx.x * blockDim.x + threadIdx.x;
    int stride = gridDim.x * blockDim.x;
    for (int j = i; j < E; j += stride) atomicAdd(&cnt[edst[j]], 1);
}

// K3: single-block exclusive scan of cnt -> rowptr, cursor. 1024 threads,
// ~49 chunk iterations; wave-shfl scan + LDS combine across 16 waves.
__global__ __launch_bounds__(1024) void k_scan(const int* __restrict__ cnt,
                                               int* __restrict__ rowptr,
                                               int* __restrict__ cursor, int N) {
    __shared__ int wsum[16];
    __shared__ int carry_s;
    if (threadIdx.x == 0) carry_s = 0;
    __syncthreads();
    int t = threadIdx.x, lane = t & 63, wid = t >> 6;
    for (int base = 0; base < N; base += 1024) {
        int idx = base + t;
        int v = (idx < N) ? cnt[idx] : 0;
        int incl = v;
        #pragma unroll
        for (int off = 1; off < 64; off <<= 1) {
            int u = __shfl_up(incl, off);
            if (lane >= off) incl += u;
        }
        if (lane == 63) wsum[wid] = incl;
        __syncthreads();
        if (wid == 0) {
            int wv = (lane < 16) ? wsum[lane] : 0;
            int wincl = wv;
            #pragma unroll
            for (int off = 1; off < 16; off <<= 1) {
                int u = __shfl_up(wincl, off);
                if (lane >= off) wincl += u;
            }
            if (lane < 16) wsum[lane] = wincl - wv;  // exclusive wave offset
        }
        __syncthreads();
        int excl = incl - v + wsum[wid] + carry_s;
        if (idx < N) { rowptr[idx] = excl; cursor[idx] = excl; }
        __syncthreads();                 // all reads of carry_s/wsum done
        if (t == 1023) carry_s = excl + v;
        __syncthreads();
    }
}

// K4: scatter edge srcs into CSR slots (int atomics, 1 per edge).
__global__ void k_scatter(const int* __restrict__ esrc, const int* __restrict__ edst,
                          int* __restrict__ cursor, int* __restrict__ colsrc, int E) {
    int i = blockIdx.x * blockDim.x + threadIdx.x;
    int stride = gridDim.x * blockDim.x;
    for (int j = i; j < E; j += stride) {
        int d = edst[j];
        int pos = atomicAdd(&cursor[d], 1);
        colsrc[pos] = esrc[j];
    }
}

// K5: layer-1 gather + finish, one thread per node. Walk in-edges (+ self
// loop), accumulate per-head {denom, numer} in registers (softmax shift-
// invariance: max-subtraction skipped, |e| small enough for fp32 exp).
// Then rank-1 feature expansion + b1 + ReLU + 512x2 linear + layer-2
// attention dots, all fused. Weights staged in LDS (uniform broadcast reads).
__global__ __launch_bounds__(256) void k_gather1(
        const int* __restrict__ rowptr, const int* __restrict__ cnt,
        const int* __restrict__ colsrc,
        const float* __restrict__ x, const float* __restrict__ consts,
        const float* __restrict__ W1, const float* __restrict__ b1,
        const float* __restrict__ W2,
        const float* __restrict__ as2, const float* __restrict__ ad2,
        float4* __restrict__ nodef, int N) {
    __shared__ float sW1[512], sB1[512], sW2[1024];
    for (int t = threadIdx.x; t < 512; t += 256) { sW1[t] = W1[t]; sB1[t] = b1[t]; }
    for (int t = threadIdx.x; t < 1024; t += 256) sW2[t] = W2[t];
    __syncthreads();
    int n = blockIdx.x * blockDim.x + threadIdx.x;
    if (n >= N) return;
    float cs[8], cd[8];
    #pragma unroll
    for (int h = 0; h < 8; ++h) { cs[h] = consts[h]; cd[h] = consts[8 + h]; }
    float xd = x[n];
    float den[8], num[8];
    // self-loop (src = dst = n)
    #pragma unroll
    for (int h = 0; h < 8; ++h) {
        float e = fmaf(xd, cs[h], xd * cd[h]);
        e = e > 0.f ? e : LRELU_SLOPE * e;
        float ex = __expf(e);
        den[h] = ex; num[h] = ex * xd;
    }
    int start = rowptr[n], deg = cnt[n];
    for (int k = 0; k < deg; ++k) {
        int s = colsrc[start + k];
        float xs = x[s];
        #pragma unroll
        for (int h = 0; h < 8; ++h) {
            float e = fmaf(xs, cs[h], xd * cd[h]);
            e = e > 0.f ? e : LRELU_SLOPE * e;
            float ex = __expf(e);
            den[h] += ex; num[h] += ex * xs;
        }
    }
    float h20 = 0.f, h21 = 0.f;
    #pragma unroll
    for (int h = 0; h < 8; ++h) {
        float sh = num[h] / (den[h] + 1e-16f);
        for (int f = 0; f < 64; ++f) {
            int idx = h * 64 + f;
            float v = fmaf(sW1[idx], sh, sB1[idx]);
            v = fmaxf(v, 0.f);
            h20 = fmaf(v, sW2[2 * idx], h20);
            h21 = fmaf(v, sW2[2 * idx + 1], h21);
        }
    }
    float as_ = h20 * as2[0] + h21 * as2[1];
    float ad_ = h20 * ad2[0] + h21 * ad2[1];
    float4 o; o.x = h20; o.y = h21; o.z = as_; o.w = ad_;
    nodef[n] = o;
}

// K6: layer-2 gather (1 head, 2 features) + log_softmax + mean reduction.
__global__ __launch_bounds__(256) void k_gather2(
        const int* __restrict__ rowptr, const int* __restrict__ cnt,
        const int* __restrict__ colsrc,
        const float4* __restrict__ nodef, const float* __restrict__ b2,
        float* __restrict__ out, int N) {
    int n = blockIdx.x * blockDim.x + threadIdx.x;
    float l0 = 0.f, l1 = 0.f;
    if (n < N) {
        float4 fd = nodef[n];
        // self-loop
        float e = fd.z + fd.w;
        e = e > 0.f ? e : LRELU_SLOPE * e;
        float ex = __expf(e);
        float den = ex, n0 = ex * fd.x, n1 = ex * fd.y;
        int start = rowptr[n], deg = cnt[n];
        for (int k = 0; k < deg; ++k) {
            int s = colsrc[start + k];
            float4 fs = nodef[s];
            e = fs.z + fd.w;
            e = e > 0.f ? e : LRELU_SLOPE * e;
            ex = __expf(e);
            den += ex; n0 += ex * fs.x; n1 += ex * fs.y;
        }
        float inv = 1.f / (den + 1e-16f);
        float o0 = n0 * inv + b2[0];
        float o1 = n1 * inv + b2[1];
        float m = fmaxf(o0, o1);
        float z0 = o0 - m, z1 = o1 - m;
        float lse = logf(__expf(z0) + __expf(z1));
        l0 = z0 - lse; l1 = z1 - lse;
    }
    #pragma unroll
    for (int off = 32; off; off >>= 1) {
        l0 += __shfl_down(l0, off);
        l1 += __shfl_down(l1, off);
    }
    __shared__ float w0[4], w1[4];
    int wid = threadIdx.x >> 6, lane = threadIdx.x & 63;
    if (lane == 0) { w0[wid] = l0; w1[wid] = l1; }
    __syncthreads();
    if (threadIdx.x == 0) {
        float s0 = w0[0] + w0[1] + w0[2] + w0[3];
        float s1 = w1[0] + w1[1] + w1[2] + w1[3];
        float invN = 1.f / (float)N;
        atomicAdd(&out[0], s0 * invN);
        atomicAdd(&out[1], s1 * invN);
    }
}

extern "C" void kernel_launch(void* const* d_in, const int* in_sizes, int n_in,
                              void* d_out, int out_size, void* d_ws, size_t ws_size,
                              hipStream_t stream) {
    const float* x   = (const float*)d_in[0];
    const int*   ei  = (const int*)d_in[1];
    const float* W1  = (const float*)d_in[2];
    const float* as1 = (const float*)d_in[3];
    const float* ad1 = (const float*)d_in[4];
    const float* b1  = (const float*)d_in[5];
    const float* W2  = (const float*)d_in[6];
    const float* as2 = (const float*)d_in[7];
    const float* ad2 = (const float*)d_in[8];
    const float* b2  = (const float*)d_in[9];
    int N = in_sizes[0];       // 50000
    int E = in_sizes[1] / 2;   // 400000
    float* out = (float*)d_out;

    char* ws = (char*)d_ws;
    float4* nodef  = (float4*)ws;                         // N*16B (16B aligned)
    int*    cnt    = (int*)(ws + (size_t)N * 16);         // N ints
    int*    rowptr = cnt + N;                             // N ints
    int*    cursor = rowptr + N;                          // N ints
    int*    colsrc = cursor + N;                          // E ints
    float*  consts = (float*)(colsrc + E);                // 16 floats

    const int* esrc = ei;
    const int* edst = ei + E;

    hipLaunchKernelGGL(k_init, dim3(256), dim3(256), 0, stream,
                       cnt, N, W1, as1, ad1, consts, out);

    int eb = (E + 255) / 256;
    hipLaunchKernelGGL(k_hist, dim3(eb), dim3(256), 0, stream, edst, cnt, E);

    hipLaunchKernelGGL(k_scan, dim3(1), dim3(1024), 0, stream,
                       cnt, rowptr, cursor, N);

    hipLaunchKernelGGL(k_scatter, dim3(eb), dim3(256), 0, stream,
                       esrc, edst, cursor, colsrc, E);

    int nb = (N + 255) / 256;
    hipLaunchKernelGGL(k_gather1, dim3(nb), dim3(256), 0, stream,
                       rowptr, cnt, colsrc, x, consts, W1, b1, W2, as2, ad2,
                       nodef, N);

    hipLaunchKernelGGL(k_gather2, dim3(nb), dim3(256), 0, stream,
                       rowptr, cnt, colsrc, nodef, b2, out, N);
}

// Round 4
// 160.083 us; speedup vs baseline: 3.3490x; 1.2242x over previous
//
#include <hip/hip_runtime.h>

#define LRELU_SLOPE 0.2f

// ---------------------------------------------------------------------------
// Gather-CSR GAT. Round-3 fix: the 49us single-block scan (0.165% occupancy)
// is replaced by a wave-level slab allocator — node n's edge slab can live
// ANYWHERE in colsrc, so ordering is unnecessary: wave-scan degrees, one
// atomicAdd on a global cursor per wave (~782 total), broadcast base.
//
// Workspace layout:
//   nodef  [N float4] : per node {h2_0, h2_1, alpha_src2, alpha_dst2}
//   cnt    [N ints]   : in-degree histogram (excl. self-loop)
//   total  [1 int]    : slab allocator cursor        (memset with cnt)
//   rowptr [N ints]   : slab start per node
//   cursor [N ints]   : scatter cursors (copy of rowptr)
//   colsrc [E ints]   : edge-source slabs
//   consts [16 floats]: cs1[8], cd1[8]
// ---------------------------------------------------------------------------

// K1: in-degree histogram; block 0 also computes per-head constants
//   cs1[h] = dot(W1[h,:,f], a_src1[h,:]) etc., and zeroes d_out.
__global__ void k_hist(const int* __restrict__ edst, int* __restrict__ cnt, int E,
                       const float* __restrict__ W1,
                       const float* __restrict__ as1,
                       const float* __restrict__ ad1,
                       float* __restrict__ consts,
                       float* __restrict__ out) {
    if (blockIdx.x == 0) {
        if (threadIdx.x < 16) {
            int h = threadIdx.x & 7;
            const float* a = (threadIdx.x < 8) ? as1 : ad1;
            float acc = 0.f;
            #pragma unroll
            for (int f = 0; f < 64; ++f) acc += W1[h * 64 + f] * a[h * 64 + f];
            consts[threadIdx.x] = acc;
        }
        if (threadIdx.x == 0) { out[0] = 0.f; out[1] = 0.f; }
    }
    int i = blockIdx.x * blockDim.x + threadIdx.x;
    int stride = gridDim.x * blockDim.x;
    for (int j = i; j < E; j += stride) atomicAdd(&cnt[edst[j]], 1);
}

// K2: slab allocator. Wave-inclusive-scan of degrees, lane 63 bumps the
// global cursor once per wave, base broadcast back down.
__global__ __launch_bounds__(256) void k_alloc(const int* __restrict__ cnt,
                                               int* __restrict__ rowptr,
                                               int* __restrict__ cursor,
                                               int* __restrict__ total, int N) {
    int n = blockIdx.x * blockDim.x + threadIdx.x;
    int lane = threadIdx.x & 63;
    int v = (n < N) ? cnt[n] : 0;
    int incl = v;
    #pragma unroll
    for (int off = 1; off < 64; off <<= 1) {
        int u = __shfl_up(incl, off);
        if (lane >= off) incl += u;
    }
    int wtot = __shfl(incl, 63);
    int base = 0;
    if (lane == 63) base = atomicAdd(total, wtot);
    base = __shfl(base, 63);
    int start = base + incl - v;
    if (n < N) { rowptr[n] = start; cursor[n] = start; }
}

// K3: scatter edge srcs into slabs (1 int atomic per edge).
__global__ void k_scatter(const int* __restrict__ esrc, const int* __restrict__ edst,
                          int* __restrict__ cursor, int* __restrict__ colsrc, int E) {
    int i = blockIdx.x * blockDim.x + threadIdx.x;
    int stride = gridDim.x * blockDim.x;
    for (int j = i; j < E; j += stride) {
        int d = edst[j];
        int pos = atomicAdd(&cursor[d], 1);
        colsrc[pos] = esrc[j];
    }
}

// K4: layer-1 gather + finish, one thread per node. Walk in-edges (+ self
// loop), accumulate per-head {denom, numer} in registers (softmax shift-
// invariance: max-subtraction skipped, |e| small enough for fp32 exp).
// Then rank-1 feature expansion + b1 + ReLU + 512x2 linear + layer-2
// attention dots, all fused. Weights staged in LDS (uniform broadcast reads).
__global__ __launch_bounds__(256) void k_gather1(
        const int* __restrict__ rowptr, const int* __restrict__ cnt,
        const int* __restrict__ colsrc,
        const float* __restrict__ x, const float* __restrict__ consts,
        const float* __restrict__ W1, const float* __restrict__ b1,
        const float* __restrict__ W2,
        const float* __restrict__ as2, const float* __restrict__ ad2,
        float4* __restrict__ nodef, int N) {
    __shared__ float sW1[512], sB1[512], sW2[1024];
    for (int t = threadIdx.x; t < 512; t += 256) { sW1[t] = W1[t]; sB1[t] = b1[t]; }
    for (int t = threadIdx.x; t < 1024; t += 256) sW2[t] = W2[t];
    __syncthreads();
    int n = blockIdx.x * blockDim.x + threadIdx.x;
    if (n >= N) return;
    float cs[8], cd[8];
    #pragma unroll
    for (int h = 0; h < 8; ++h) { cs[h] = consts[h]; cd[h] = consts[8 + h]; }
    float xd = x[n];
    float den[8], num[8];
    // self-loop (src = dst = n)
    #pragma unroll
    for (int h = 0; h < 8; ++h) {
        float e = fmaf(xd, cs[h], xd * cd[h]);
        e = e > 0.f ? e : LRELU_SLOPE * e;
        float ex = __expf(e);
        den[h] = ex; num[h] = ex * xd;
    }
    int start = rowptr[n], deg = cnt[n];
    for (int k = 0; k < deg; ++k) {
        int s = colsrc[start + k];
        float xs = x[s];
        #pragma unroll
        for (int h = 0; h < 8; ++h) {
            float e = fmaf(xs, cs[h], xd * cd[h]);
            e = e > 0.f ? e : LRELU_SLOPE * e;
            float ex = __expf(e);
            den[h] += ex; num[h] += ex * xs;
        }
    }
    float h20 = 0.f, h21 = 0.f;
    #pragma unroll
    for (int h = 0; h < 8; ++h) {
        float sh = num[h] / (den[h] + 1e-16f);
        for (int f = 0; f < 64; ++f) {
            int idx = h * 64 + f;
            float v = fmaf(sW1[idx], sh, sB1[idx]);
            v = fmaxf(v, 0.f);
            h20 = fmaf(v, sW2[2 * idx], h20);
            h21 = fmaf(v, sW2[2 * idx + 1], h21);
        }
    }
    float as_ = h20 * as2[0] + h21 * as2[1];
    float ad_ = h20 * ad2[0] + h21 * ad2[1];
    float4 o; o.x = h20; o.y = h21; o.z = as_; o.w = ad_;
    nodef[n] = o;
}

// K5: layer-2 gather (1 head, 2 features) + log_softmax + mean reduction.
__global__ __launch_bounds__(256) void k_gather2(
        const int* __restrict__ rowptr, const int* __restrict__ cnt,
        const int* __restrict__ colsrc,
        const float4* __restrict__ nodef, const float* __restrict__ b2,
        float* __restrict__ out, int N) {
    int n = blockIdx.x * blockDim.x + threadIdx.x;
    float l0 = 0.f, l1 = 0.f;
    if (n < N) {
        float4 fd = nodef[n];
        // self-loop
        float e = fd.z + fd.w;
        e = e > 0.f ? e : LRELU_SLOPE * e;
        float ex = __expf(e);
        float den = ex, n0 = ex * fd.x, n1 = ex * fd.y;
        int start = rowptr[n], deg = cnt[n];
        for (int k = 0; k < deg; ++k) {
            int s = colsrc[start + k];
            float4 fs = nodef[s];
            e = fs.z + fd.w;
            e = e > 0.f ? e : LRELU_SLOPE * e;
            ex = __expf(e);
            den += ex; n0 += ex * fs.x; n1 += ex * fs.y;
        }
        float inv = 1.f / (den + 1e-16f);
        float o0 = n0 * inv + b2[0];
        float o1 = n1 * inv + b2[1];
        float m = fmaxf(o0, o1);
        float z0 = o0 - m, z1 = o1 - m;
        float lse = logf(__expf(z0) + __expf(z1));
        l0 = z0 - lse; l1 = z1 - lse;
    }
    #pragma unroll
    for (int off = 32; off; off >>= 1) {
        l0 += __shfl_down(l0, off);
        l1 += __shfl_down(l1, off);
    }
    __shared__ float w0[4], w1[4];
    int wid = threadIdx.x >> 6, lane = threadIdx.x & 63;
    if (lane == 0) { w0[wid] = l0; w1[wid] = l1; }
    __syncthreads();
    if (threadIdx.x == 0) {
        float s0 = w0[0] + w0[1] + w0[2] + w0[3];
        float s1 = w1[0] + w1[1] + w1[2] + w1[3];
        float invN = 1.f / (float)N;
        atomicAdd(&out[0], s0 * invN);
        atomicAdd(&out[1], s1 * invN);
    }
}

extern "C" void kernel_launch(void* const* d_in, const int* in_sizes, int n_in,
                              void* d_out, int out_size, void* d_ws, size_t ws_size,
                              hipStream_t stream) {
    const float* x   = (const float*)d_in[0];
    const int*   ei  = (const int*)d_in[1];
    const float* W1  = (const float*)d_in[2];
    const float* as1 = (const float*)d_in[3];
    const float* ad1 = (const float*)d_in[4];
    const float* b1  = (const float*)d_in[5];
    const float* W2  = (const float*)d_in[6];
    const float* as2 = (const float*)d_in[7];
    const float* ad2 = (const float*)d_in[8];
    const float* b2  = (const float*)d_in[9];
    int N = in_sizes[0];       // 50000
    int E = in_sizes[1] / 2;   // 400000
    float* out = (float*)d_out;

    char* ws = (char*)d_ws;
    float4* nodef  = (float4*)ws;                    // N*16B (16B aligned)
    int*    cnt    = (int*)(ws + (size_t)N * 16);    // N ints
    int*    total  = cnt + N;                        // 1 int (memset with cnt)
    int*    rowptr = total + 1;                      // N ints
    int*    cursor = rowptr + N;                     // N ints
    int*    colsrc = cursor + N;                     // E ints
    float*  consts = (float*)(colsrc + E);           // 16 floats

    const int* esrc = ei;
    const int* edst = ei + E;

    // zero cnt + total in one async memset (capture-safe)
    hipMemsetAsync(cnt, 0, (size_t)(N + 1) * sizeof(int), stream);

    int eb = (E + 255) / 256;
    hipLaunchKernelGGL(k_hist, dim3(eb), dim3(256), 0, stream,
                       edst, cnt, E, W1, as1, ad1, consts, out);

    int nb = (N + 255) / 256;
    hipLaunchKernelGGL(k_alloc, dim3(nb), dim3(256), 0, stream,
                       cnt, rowptr, cursor, total, N);

    hipLaunchKernelGGL(k_scatter, dim3(eb), dim3(256), 0, stream,
                       esrc, edst, cursor, colsrc, E);

    hipLaunchKernelGGL(k_gather1, dim3(nb), dim3(256), 0, stream,
                       rowptr, cnt, colsrc, x, consts, W1, b1, W2, as2, ad2,
                       nodef, N);

    hipLaunchKernelGGL(k_gather2, dim3(nb), dim3(256), 0, stream,
                       rowptr, cnt, colsrc, nodef, b2, out, N);
}